// Round 6
// baseline (1763.827 us; speedup 1.0000x reference)
//
#include <hip/hip_runtime.h>
#include <hip/hip_bf16.h>

#define NN 131072
#define KK 27
#define CC 32
#define EPSV 1e-5f

// fixed-point encoding: field = n*FOFF + S*sum(v) in 21 bits, monotone adds
#define FS    4096.0f          // scale (pow2 -> exact decode divide)
#define FOFF  10240.0f         // per-add offset = 2.5*FS (clamp bound)
#define FMASK 0x1FFFFFu

// ws layout (bytes)
#define WS_STATS 0             // 64 f32
#define WS_WFRAG 256           // 27*3*64*8 shorts = 82944 B (global B-frags)
#define WS_ACC   83200         // 11 SoA planes * NN * 8 B = 11534336 B
#define WS_NEEDED ((size_t)WS_ACC + 11ull * NN * 8ull)   // 11617536 (16B mult)

typedef __bf16 bf16x8 __attribute__((ext_vector_type(8)));
typedef short s16x8 __attribute__((ext_vector_type(8)));
typedef float f32x4 __attribute__((ext_vector_type(4)));

__device__ inline unsigned short f2bf(float f) {
    unsigned int u = __float_as_uint(f);
    u += 0x7FFF + ((u >> 16) & 1);   // round-to-nearest-even
    return (unsigned short)(u >> 16);
}

__device__ inline unsigned int quantf(float v) {
    v = fminf(fmaxf(v, -2.5f), 2.5f);
    return (unsigned int)(int)rintf(fmaf(v, FS, FOFF));   // [0, 20480]
}

// ---------------------------------------------------------------------------
__global__ __launch_bounds__(256) void zero_kernel(float4* __restrict__ p, int n4) {
    const int idx = blockIdx.x * 256 + threadIdx.x;
    const float4 z = {0.f, 0.f, 0.f, 0.f};
    if (idx < n4) p[idx] = z;
}

// ---------------------------------------------------------------------------
// Build bf16 B-fragments in GLOBAL ws (83 KB — exceeds the 64 KB LDS cap).
// Channel permutation for u64 triples: logical channel c lives in matrix
// (c % 3) at column (c / 3); columns 11..15 and the (col10, mat2) slot are
// ZERO (the latter becomes the exact per-row contribution counter: each add
// deposits exactly FOFF there).
// Frag layout per matrix (16x16x32 B-op): lane = col | (kq<<4) holds
// B[kq*8+j][col] at slot j.
__global__ __launch_bounds__(256) void prep_wfrag(
    const float* __restrict__ w, unsigned short* __restrict__ wf)
{
    const int p = blockIdx.x * 256 + threadIdx.x;   // 27*3*64*8 = 41472
    if (p >= KK * 3 * 512) return;
    const int j = p & 7;
    const int lane = (p >> 3) & 63;
    const int km = p >> 9;          // k*3 + mat
    const int mat = km - (km / 3) * 3;
    const int k = km / 3;
    const int col = lane & 15;
    const int ci = (lane >> 4) * 8 + j;
    const int c = 3 * col + mat;
    unsigned short v = 0;
    if (col < 11 && c < 32) v = f2bf(w[(k * 32 + ci) * 32 + c]);
    wf[p] = v;
}

// ---------------------------------------------------------------------------
// Scatter with u64 fixed-point atomics: per (node, tap) destination row,
// 11 u64 atomics (3 channels each, 11th carries 2 ch + count field) instead
// of 16 pk-f16 ops. 3 MFMAs per row-group give lane t its channel triple
// (3t, 3t+1, 3t+2) natively — no cross-lane traffic.
// Accumulator is SoA: plane t at acc[t*NN + row].
__global__ __launch_bounds__(256) void scatter_kernel(
    const float* __restrict__ data, const unsigned short* __restrict__ wf,
    const int* __restrict__ neigh, unsigned long long* __restrict__ acc)
{
    const int tid = threadIdx.x;
    const int lane = tid & 63;
    const int wv = tid >> 6;
    const int quad = lane >> 4, m = lane & 15, rq = quad << 2;
    const int node_base = blockIdx.x * 128 + wv * 32;

    // A-fragments: A[m=lane&15][kel=quad*8+j], f32->bf16 inline
    s16x8 afr[2];
    #pragma unroll
    for (int g = 0; g < 2; ++g) {
        const int node = node_base + g * 16 + m;
        const float* src = data + node * 32 + quad * 8;
        const float4 v0 = *(const float4*)(src);
        const float4 v1 = *(const float4*)(src + 4);
        s16x8 s;
        s[0] = (short)f2bf(v0.x); s[1] = (short)f2bf(v0.y);
        s[2] = (short)f2bf(v0.z); s[3] = (short)f2bf(v0.w);
        s[4] = (short)f2bf(v1.x); s[5] = (short)f2bf(v1.y);
        s[6] = (short)f2bf(v1.z); s[7] = (short)f2bf(v1.w);
        afr[g] = s;
    }

    const f32x4 zero = {0.f, 0.f, 0.f, 0.f};
    const size_t plane = (size_t)m * NN;

    for (int k = 0; k < KK; ++k) {
        int nj[2][4];
        #pragma unroll
        for (int g = 0; g < 2; ++g)
            #pragma unroll
            for (int r = 0; r < 4; ++r)
                nj[g][r] = neigh[(node_base + g * 16 + rq + r) * KK + k];

        const s16x8 b0 = *(const s16x8*)(wf + ((k * 3 + 0) * 64 + lane) * 8);
        const s16x8 b1 = *(const s16x8*)(wf + ((k * 3 + 1) * 64 + lane) * 8);
        const s16x8 b2 = *(const s16x8*)(wf + ((k * 3 + 2) * 64 + lane) * 8);

        #pragma unroll
        for (int g = 0; g < 2; ++g) {
            const f32x4 d0 = __builtin_amdgcn_mfma_f32_16x16x32_bf16(
                __builtin_bit_cast(bf16x8, afr[g]), __builtin_bit_cast(bf16x8, b0),
                zero, 0, 0, 0);
            const f32x4 d1 = __builtin_amdgcn_mfma_f32_16x16x32_bf16(
                __builtin_bit_cast(bf16x8, afr[g]), __builtin_bit_cast(bf16x8, b1),
                zero, 0, 0, 0);
            const f32x4 d2 = __builtin_amdgcn_mfma_f32_16x16x32_bf16(
                __builtin_bit_cast(bf16x8, afr[g]), __builtin_bit_cast(bf16x8, b2),
                zero, 0, 0, 0);
            #pragma unroll
            for (int r = 0; r < 4; ++r) {
                const unsigned long long q0 = quantf(d0[r]);
                const unsigned long long q1 = quantf(d1[r]);
                const unsigned long long q2 = quantf(d2[r]);
                const unsigned long long qq = q0 | (q1 << 21) | (q2 << 42);
                if (m < 11)
                    atomicAdd(&acc[plane + nj[g][r]], qq);
            }
        }
    }
}

// ---------------------------------------------------------------------------
__device__ inline float dec_n(unsigned long long uc) {
    return rintf((float)(unsigned int)(uc >> 42) * (1.0f / FOFF));
}
__device__ inline void decode3(unsigned long long u, float n, float* v) {
    const float nb = n * FOFF;
    v[0] = ((float)(int)((unsigned int)u & FMASK)          - nb) * (1.0f / FS);
    v[1] = ((float)(int)((unsigned int)(u >> 21) & FMASK)  - nb) * (1.0f / FS);
    v[2] = ((float)(int)(unsigned int)(u >> 42)            - nb) * (1.0f / FS);
}

// Per-channel sum/sumsq with decode. Block covers 512 rows; thread = (t, rg).
__global__ __launch_bounds__(256) void stats_kernel(
    const unsigned long long* __restrict__ acc, float* __restrict__ stats)
{
    __shared__ float ls[16][33], ls2[16][33];
    const int tid = threadIdx.x;
    const int t = tid & 15, rg = tid >> 4;
    float s[3] = {0.f, 0.f, 0.f}, s2[3] = {0.f, 0.f, 0.f};
    const int row0 = blockIdx.x * 512;
    const int nv = (t == 10) ? 2 : 3;
    if (t <= 10) {
        for (int it = 0; it < 32; ++it) {
            const int row = row0 + it * 16 + rg;
            const unsigned long long u  = acc[(size_t)t * NN + row];
            const unsigned long long uc = acc[(size_t)10 * NN + row];
            const float n = dec_n(uc);
            float v[3];
            decode3(u, n, v);
            for (int i = 0; i < nv; ++i) { s[i] += v[i]; s2[i] += v[i] * v[i]; }
        }
        const int c0 = 3 * t;
        for (int i = 0; i < nv; ++i) { ls[rg][c0 + i] = s[i]; ls2[rg][c0 + i] = s2[i]; }
    }
    __syncthreads();
    if (tid < 32) {
        float S = 0.f, S2 = 0.f;
        #pragma unroll
        for (int g = 0; g < 16; ++g) { S += ls[g][tid]; S2 += ls2[g][tid]; }
        atomicAdd(&stats[tid], S);
        atomicAdd(&stats[32 + tid], S2);
    }
}

// BN + ReLU with decode; writes f32 out. Block covers 256 rows.
__global__ __launch_bounds__(256) void bn_relu_kernel(
    const unsigned long long* __restrict__ acc, float* __restrict__ out,
    const float* __restrict__ stats,
    const float* __restrict__ gamma, const float* __restrict__ beta)
{
    __shared__ float sc[32], sh[32];
    const int tid = threadIdx.x;
    if (tid < 32) {
        const float mean = stats[tid] * (1.0f / NN);
        const float var  = stats[32 + tid] * (1.0f / NN) - mean * mean;
        const float s = gamma[tid] * rsqrtf(var + EPSV);
        sc[tid] = s;
        sh[tid] = beta[tid] - mean * s;
    }
    __syncthreads();
    const int t = tid & 15, rg = tid >> 4;
    if (t > 10) return;
    const int nv = (t == 10) ? 2 : 3;
    const int c0 = 3 * t;
    for (int it = 0; it < 16; ++it) {
        const int row = blockIdx.x * 256 + it * 16 + rg;
        const unsigned long long u  = acc[(size_t)t * NN + row];
        const unsigned long long uc = acc[(size_t)10 * NN + row];
        const float n = dec_n(uc);
        float v[3];
        decode3(u, n, v);
        for (int i = 0; i < nv; ++i) {
            const int c = c0 + i;
            out[row * 32 + c] = fmaxf(fmaf(v[i], sc[c], sh[c]), 0.f);
        }
    }
}

// ===========================================================================
// Fallback (f32 atomics into d_out) — only if ws is too small.
__global__ __launch_bounds__(256) void scatter_f32_kernel(
    const float* __restrict__ data, const float* __restrict__ weight,
    const int* __restrict__ neigh, float* __restrict__ out)
{
    __shared__ unsigned short wfrag[KK * 2 * 64 * 8];
    const int tid = threadIdx.x;
    const int lane = tid & 63;
    const int wv = tid >> 6;
    const int node_base = blockIdx.x * 128;
    for (int p = tid; p < KK * 1024; p += 256) {
        const int k  = p >> 10;
        const int ci = (p >> 5) & 31;
        const int c  = p & 31;
        const unsigned short v = f2bf(weight[p]);
        const int chalf = c >> 4;
        const int fl = (c & 15) | ((ci >> 3) << 4);
        const int j = ci & 7;
        wfrag[(((k << 1) | chalf) * 64 + fl) * 8 + j] = v;
    }
    const int quad = lane >> 4;
    const int m = lane & 15;
    s16x8 afr[2];
    #pragma unroll
    for (int g = 0; g < 2; ++g) {
        const int node = node_base + wv * 32 + g * 16 + m;
        const float* src = data + node * 32 + quad * 8;
        const float4 v0 = *(const float4*)(src);
        const float4 v1 = *(const float4*)(src + 4);
        s16x8 s;
        s[0] = (short)f2bf(v0.x); s[1] = (short)f2bf(v0.y);
        s[2] = (short)f2bf(v0.z); s[3] = (short)f2bf(v0.w);
        s[4] = (short)f2bf(v1.x); s[5] = (short)f2bf(v1.y);
        s[6] = (short)f2bf(v1.z); s[7] = (short)f2bf(v1.w);
        afr[g] = s;
    }
    __syncthreads();
    const int rq = quad << 2;
    const f32x4 zero = {0.f, 0.f, 0.f, 0.f};
    for (int k = 0; k < KK; ++k) {
        int nj[2][4];
        #pragma unroll
        for (int g = 0; g < 2; ++g)
            #pragma unroll
            for (int r = 0; r < 4; ++r) {
                const int node = node_base + wv * 32 + g * 16 + rq + r;
                nj[g][r] = neigh[node * KK + k];
            }
        #pragma unroll
        for (int ch = 0; ch < 2; ++ch) {
            const s16x8 bs = *(const s16x8*)&wfrag[((((k << 1) | ch)) * 64 + lane) * 8];
            const bf16x8 bfr = __builtin_bit_cast(bf16x8, bs);
            const int c = (ch << 4) | m;
            #pragma unroll
            for (int g = 0; g < 2; ++g) {
                f32x4 a2 = __builtin_amdgcn_mfma_f32_16x16x32_bf16(
                    __builtin_bit_cast(bf16x8, afr[g]), bfr, zero, 0, 0, 0);
                #pragma unroll
                for (int r = 0; r < 4; ++r)
                    __hip_atomic_fetch_add(&out[nj[g][r] * 32 + c], a2[r],
                                           __ATOMIC_RELAXED, __HIP_MEMORY_SCOPE_AGENT);
            }
        }
    }
}

__global__ __launch_bounds__(256) void stats_f32_kernel(
    const float* __restrict__ out, float* __restrict__ stats)
{
    __shared__ float ls[256], ls2[256];
    const int tid = threadIdx.x;
    const int c = tid & 31, rg = tid >> 5;
    float s = 0.f, s2 = 0.f;
    const int row0 = blockIdx.x * 512;
    for (int it = 0; it < 64; ++it) {
        const float v = out[(row0 + it * 8 + rg) * 32 + c];
        s += v; s2 += v * v;
    }
    ls[tid] = s; ls2[tid] = s2;
    __syncthreads();
    if (tid < 32) {
        float S = 0.f, S2 = 0.f;
        #pragma unroll
        for (int r = 0; r < 8; ++r) { S += ls[r * 32 + tid]; S2 += ls2[r * 32 + tid]; }
        atomicAdd(&stats[tid], S);
        atomicAdd(&stats[32 + tid], S2);
    }
}

__global__ __launch_bounds__(256) void bn_relu_f32_kernel(
    float* __restrict__ out, const float* __restrict__ stats,
    const float* __restrict__ gamma, const float* __restrict__ beta)
{
    __shared__ float sc[32], sh[32];
    const int tid = threadIdx.x;
    if (tid < 32) {
        const float mean = stats[tid] * (1.0f / NN);
        const float var  = stats[32 + tid] * (1.0f / NN) - mean * mean;
        const float s = gamma[tid] * rsqrtf(var + EPSV);
        sc[tid] = s;
        sh[tid] = beta[tid] - mean * s;
    }
    __syncthreads();
    const int idx = blockIdx.x * 256 + tid;
    float4 v = ((float4*)out)[idx];
    const int cb = (idx & 7) << 2;
    v.x = fmaxf(v.x * sc[cb]     + sh[cb],     0.f);
    v.y = fmaxf(v.y * sc[cb + 1] + sh[cb + 1], 0.f);
    v.z = fmaxf(v.z * sc[cb + 2] + sh[cb + 2], 0.f);
    v.w = fmaxf(v.w * sc[cb + 3] + sh[cb + 3], 0.f);
    ((float4*)out)[idx] = v;
}

// ===========================================================================
extern "C" void kernel_launch(void* const* d_in, const int* in_sizes, int n_in,
                              void* d_out, int out_size, void* d_ws, size_t ws_size,
                              hipStream_t stream) {
    const float* data   = (const float*)d_in[0];
    const float* weight = (const float*)d_in[1];
    const float* gamma  = (const float*)d_in[2];
    const float* beta   = (const float*)d_in[3];
    const int*   neigh  = (const int*)d_in[4];
    float* out = (float*)d_out;
    char* ws = (char*)d_ws;
    float* stats = (float*)(ws + WS_STATS);

    if (ws_size >= WS_NEEDED) {
        unsigned short* wf = (unsigned short*)(ws + WS_WFRAG);
        unsigned long long* acc = (unsigned long long*)(ws + WS_ACC);
        const int n4 = (int)(WS_NEEDED / 16);
        zero_kernel<<<(n4 + 255) / 256, 256, 0, stream>>>((float4*)ws, n4);
        prep_wfrag<<<(KK * 3 * 512 + 255) / 256, 256, 0, stream>>>(weight, wf);
        scatter_kernel<<<NN / 128, 256, 0, stream>>>(data, wf, neigh, acc);
        stats_kernel<<<NN / 512, 256, 0, stream>>>(acc, stats);
        bn_relu_kernel<<<NN / 256, 256, 0, stream>>>(acc, out, stats, gamma, beta);
    } else {
        const int n4o = NN * CC / 4;
        zero_kernel<<<(n4o + 255) / 256, 256, 0, stream>>>((float4*)out, n4o);
        zero_kernel<<<1, 256, 0, stream>>>((float4*)stats, 16);
        scatter_f32_kernel<<<NN / 128, 256, 0, stream>>>(data, weight, neigh, out);
        stats_f32_kernel<<<NN / 512, 256, 0, stream>>>(out, stats);
        bn_relu_f32_kernel<<<(NN * CC / 4) / 256, 256, 0, stream>>>(out, stats, gamma, beta);
    }
}

// Round 7
// 426.125 us; speedup vs baseline: 4.1392x; 4.1392x over previous
//
#include <hip/hip_runtime.h>
#include <hip/hip_bf16.h>

#define NN 131072
#define KK 27
#define CC 32
#define EPSV 1e-5f

// fixed-point encoding: field = n*FOFF + FS*sum(v) in 21 bits, monotone adds
#define FS    4096.0f          // scale (pow2 -> exact decode divide)
#define FOFF  10240.0f         // per-add offset = 2.5*FS (clamp bound)
#define FMASK 0x1FFFFFu
#define RSTRIDE 12             // u64 per row (11 used + 1 pad -> 96 B aligned rows)

// ws layout (bytes)
#define WS_STATS 0             // 64 f32
#define WS_WFRAG 256           // 27*3*64*8 shorts = 82944 B (global B-frags)
#define WS_ACC   83200         // NN rows * 12 u64 = 12582912 B
#define WS_NEEDED ((size_t)WS_ACC + (size_t)NN * RSTRIDE * 8ull)

typedef __bf16 bf16x8 __attribute__((ext_vector_type(8)));
typedef short s16x8 __attribute__((ext_vector_type(8)));
typedef float f32x4 __attribute__((ext_vector_type(4)));

__device__ inline unsigned short f2bf(float f) {
    unsigned int u = __float_as_uint(f);
    u += 0x7FFF + ((u >> 16) & 1);   // round-to-nearest-even
    return (unsigned short)(u >> 16);
}

__device__ inline unsigned int quantf(float v) {
    v = fminf(fmaxf(v, -2.5f), 2.5f);
    return (unsigned int)(int)rintf(fmaf(v, FS, FOFF));   // [0, 20480]
}

// ---------------------------------------------------------------------------
__global__ __launch_bounds__(256) void zero_kernel(float4* __restrict__ p, int n4) {
    const int idx = blockIdx.x * 256 + threadIdx.x;
    const float4 z = {0.f, 0.f, 0.f, 0.f};
    if (idx < n4) p[idx] = z;
}

// ---------------------------------------------------------------------------
// Build bf16 B-fragments in GLOBAL ws. Channel permutation for u64 triples:
// logical channel c lives in matrix (c % 3) at column (c / 3); columns 11..15
// and the (col10, mat2) slot are ZERO (the latter is the exact per-row count
// field: every add deposits exactly FOFF there).
__global__ __launch_bounds__(256) void prep_wfrag(
    const float* __restrict__ w, unsigned short* __restrict__ wf)
{
    const int p = blockIdx.x * 256 + threadIdx.x;   // 27*3*64*8 = 41472
    if (p >= KK * 3 * 512) return;
    const int j = p & 7;
    const int lane = (p >> 3) & 63;
    const int km = p >> 9;          // k*3 + mat
    const int mat = km - (km / 3) * 3;
    const int k = km / 3;
    const int col = lane & 15;
    const int ci = (lane >> 4) * 8 + j;
    const int c = 3 * col + mat;
    unsigned short v = 0;
    if (col < 11 && c < 32) v = f2bf(w[(k * 32 + ci) * 32 + c]);
    wf[p] = v;
}

// ---------------------------------------------------------------------------
// Scatter with u64 fixed-point atomics, AoS rows: acc[row*12 + t], t=0..10.
// Per (node, tap): lanes t=0..10 of the owning quad issue 11 contiguous u64
// atomics covering 88 B inside the row's aligned 96 B window (3 sectors).
// 3 MFMAs per row-group give lane t its channel triple (3t,3t+1,3t+2)
// natively — no cross-lane traffic.
__global__ __launch_bounds__(256) void scatter_kernel(
    const float* __restrict__ data, const unsigned short* __restrict__ wf,
    const int* __restrict__ neigh, unsigned long long* __restrict__ acc)
{
    const int tid = threadIdx.x;
    const int lane = tid & 63;
    const int wv = tid >> 6;
    const int quad = lane >> 4, m = lane & 15, rq = quad << 2;
    const int node_base = blockIdx.x * 128 + wv * 32;

    // A-fragments: A[m=lane&15][kel=quad*8+j], f32->bf16 inline
    s16x8 afr[2];
    #pragma unroll
    for (int g = 0; g < 2; ++g) {
        const int node = node_base + g * 16 + m;
        const float* src = data + node * 32 + quad * 8;
        const float4 v0 = *(const float4*)(src);
        const float4 v1 = *(const float4*)(src + 4);
        s16x8 s;
        s[0] = (short)f2bf(v0.x); s[1] = (short)f2bf(v0.y);
        s[2] = (short)f2bf(v0.z); s[3] = (short)f2bf(v0.w);
        s[4] = (short)f2bf(v1.x); s[5] = (short)f2bf(v1.y);
        s[6] = (short)f2bf(v1.z); s[7] = (short)f2bf(v1.w);
        afr[g] = s;
    }

    const f32x4 zero = {0.f, 0.f, 0.f, 0.f};

    for (int k = 0; k < KK; ++k) {
        int nj[2][4];
        #pragma unroll
        for (int g = 0; g < 2; ++g)
            #pragma unroll
            for (int r = 0; r < 4; ++r)
                nj[g][r] = neigh[(node_base + g * 16 + rq + r) * KK + k];

        const s16x8 b0 = *(const s16x8*)(wf + ((k * 3 + 0) * 64 + lane) * 8);
        const s16x8 b1 = *(const s16x8*)(wf + ((k * 3 + 1) * 64 + lane) * 8);
        const s16x8 b2 = *(const s16x8*)(wf + ((k * 3 + 2) * 64 + lane) * 8);

        #pragma unroll
        for (int g = 0; g < 2; ++g) {
            const f32x4 d0 = __builtin_amdgcn_mfma_f32_16x16x32_bf16(
                __builtin_bit_cast(bf16x8, afr[g]), __builtin_bit_cast(bf16x8, b0),
                zero, 0, 0, 0);
            const f32x4 d1 = __builtin_amdgcn_mfma_f32_16x16x32_bf16(
                __builtin_bit_cast(bf16x8, afr[g]), __builtin_bit_cast(bf16x8, b1),
                zero, 0, 0, 0);
            const f32x4 d2 = __builtin_amdgcn_mfma_f32_16x16x32_bf16(
                __builtin_bit_cast(bf16x8, afr[g]), __builtin_bit_cast(bf16x8, b2),
                zero, 0, 0, 0);
            #pragma unroll
            for (int r = 0; r < 4; ++r) {
                const unsigned long long q0 = quantf(d0[r]);
                const unsigned long long q1 = quantf(d1[r]);
                const unsigned long long q2 = quantf(d2[r]);
                const unsigned long long qq = q0 | (q1 << 21) | (q2 << 42);
                if (m < 11)
                    atomicAdd(&acc[(size_t)nj[g][r] * RSTRIDE + m], qq);
            }
        }
    }
}

// ---------------------------------------------------------------------------
__device__ inline float dec_n(unsigned long long uc) {
    return rintf((float)(unsigned int)(uc >> 42) * (1.0f / FOFF));
}
__device__ inline void decode3(unsigned long long u, float n, float* v) {
    const float nb = n * FOFF;
    v[0] = ((float)(int)((unsigned int)u & FMASK)          - nb) * (1.0f / FS);
    v[1] = ((float)(int)((unsigned int)(u >> 21) & FMASK)  - nb) * (1.0f / FS);
    v[2] = ((float)(int)(unsigned int)(u >> 42)            - nb) * (1.0f / FS);
}

// Per-channel sum/sumsq with decode. Block covers 512 rows; thread = (t, rg).
__global__ __launch_bounds__(256) void stats_kernel(
    const unsigned long long* __restrict__ acc, float* __restrict__ stats)
{
    __shared__ float ls[16][33], ls2[16][33];
    const int tid = threadIdx.x;
    const int t = tid & 15, rg = tid >> 4;
    float s[3] = {0.f, 0.f, 0.f}, s2[3] = {0.f, 0.f, 0.f};
    const int row0 = blockIdx.x * 512;
    const int nv = (t == 10) ? 2 : 3;
    if (t <= 10) {
        for (int it = 0; it < 32; ++it) {
            const size_t rb = (size_t)(row0 + it * 16 + rg) * RSTRIDE;
            const unsigned long long u  = acc[rb + t];
            const unsigned long long uc = acc[rb + 10];
            const float n = dec_n(uc);
            float v[3];
            decode3(u, n, v);
            for (int i = 0; i < nv; ++i) { s[i] += v[i]; s2[i] += v[i] * v[i]; }
        }
        const int c0 = 3 * t;
        for (int i = 0; i < nv; ++i) { ls[rg][c0 + i] = s[i]; ls2[rg][c0 + i] = s2[i]; }
    }
    __syncthreads();
    if (tid < 32) {
        float S = 0.f, S2 = 0.f;
        #pragma unroll
        for (int g = 0; g < 16; ++g) { S += ls[g][tid]; S2 += ls2[g][tid]; }
        atomicAdd(&stats[tid], S);
        atomicAdd(&stats[32 + tid], S2);
    }
}

// BN + ReLU with decode; writes f32 out. Block covers 256 rows.
__global__ __launch_bounds__(256) void bn_relu_kernel(
    const unsigned long long* __restrict__ acc, float* __restrict__ out,
    const float* __restrict__ stats,
    const float* __restrict__ gamma, const float* __restrict__ beta)
{
    __shared__ float sc[32], sh[32];
    const int tid = threadIdx.x;
    if (tid < 32) {
        const float mean = stats[tid] * (1.0f / NN);
        const float var  = stats[32 + tid] * (1.0f / NN) - mean * mean;
        const float s = gamma[tid] * rsqrtf(var + EPSV);
        sc[tid] = s;
        sh[tid] = beta[tid] - mean * s;
    }
    __syncthreads();
    const int t = tid & 15, rg = tid >> 4;
    if (t > 10) return;
    const int nv = (t == 10) ? 2 : 3;
    const int c0 = 3 * t;
    for (int it = 0; it < 16; ++it) {
        const int row = blockIdx.x * 256 + it * 16 + rg;
        const size_t rb = (size_t)row * RSTRIDE;
        const unsigned long long u  = acc[rb + t];
        const unsigned long long uc = acc[rb + 10];
        const float n = dec_n(uc);
        float v[3];
        decode3(u, n, v);
        for (int i = 0; i < nv; ++i) {
            const int c = c0 + i;
            out[row * 32 + c] = fmaxf(fmaf(v[i], sc[c], sh[c]), 0.f);
        }
    }
}

// ===========================================================================
// Fallback (f32 atomics into d_out) — only if ws is too small.
__global__ __launch_bounds__(256) void scatter_f32_kernel(
    const float* __restrict__ data, const float* __restrict__ weight,
    const int* __restrict__ neigh, float* __restrict__ out)
{
    __shared__ unsigned short wfrag[KK * 2 * 64 * 8];
    const int tid = threadIdx.x;
    const int lane = tid & 63;
    const int wv = tid >> 6;
    const int node_base = blockIdx.x * 128;
    for (int p = tid; p < KK * 1024; p += 256) {
        const int k  = p >> 10;
        const int ci = (p >> 5) & 31;
        const int c  = p & 31;
        const unsigned short v = f2bf(weight[p]);
        const int chalf = c >> 4;
        const int fl = (c & 15) | ((ci >> 3) << 4);
        const int j = ci & 7;
        wfrag[(((k << 1) | chalf) * 64 + fl) * 8 + j] = v;
    }
    const int quad = lane >> 4;
    const int m = lane & 15;
    s16x8 afr[2];
    #pragma unroll
    for (int g = 0; g < 2; ++g) {
        const int node = node_base + wv * 32 + g * 16 + m;
        const float* src = data + node * 32 + quad * 8;
        const float4 v0 = *(const float4*)(src);
        const float4 v1 = *(const float4*)(src + 4);
        s16x8 s;
        s[0] = (short)f2bf(v0.x); s[1] = (short)f2bf(v0.y);
        s[2] = (short)f2bf(v0.z); s[3] = (short)f2bf(v0.w);
        s[4] = (short)f2bf(v1.x); s[5] = (short)f2bf(v1.y);
        s[6] = (short)f2bf(v1.z); s[7] = (short)f2bf(v1.w);
        afr[g] = s;
    }
    __syncthreads();
    const int rq = quad << 2;
    const f32x4 zero = {0.f, 0.f, 0.f, 0.f};
    for (int k = 0; k < KK; ++k) {
        int nj[2][4];
        #pragma unroll
        for (int g = 0; g < 2; ++g)
            #pragma unroll
            for (int r = 0; r < 4; ++r) {
                const int node = node_base + wv * 32 + g * 16 + rq + r;
                nj[g][r] = neigh[node * KK + k];
            }
        #pragma unroll
        for (int ch = 0; ch < 2; ++ch) {
            const s16x8 bs = *(const s16x8*)&wfrag[((((k << 1) | ch)) * 64 + lane) * 8];
            const bf16x8 bfr = __builtin_bit_cast(bf16x8, bs);
            const int c = (ch << 4) | m;
            #pragma unroll
            for (int g = 0; g < 2; ++g) {
                f32x4 a2 = __builtin_amdgcn_mfma_f32_16x16x32_bf16(
                    __builtin_bit_cast(bf16x8, afr[g]), bfr, zero, 0, 0, 0);
                #pragma unroll
                for (int r = 0; r < 4; ++r)
                    __hip_atomic_fetch_add(&out[nj[g][r] * 32 + c], a2[r],
                                           __ATOMIC_RELAXED, __HIP_MEMORY_SCOPE_AGENT);
            }
        }
    }
}

__global__ __launch_bounds__(256) void stats_f32_kernel(
    const float* __restrict__ out, float* __restrict__ stats)
{
    __shared__ float ls[256], ls2[256];
    const int tid = threadIdx.x;
    const int c = tid & 31, rg = tid >> 5;
    float s = 0.f, s2 = 0.f;
    const int row0 = blockIdx.x * 512;
    for (int it = 0; it < 64; ++it) {
        const float v = out[(row0 + it * 8 + rg) * 32 + c];
        s += v; s2 += v * v;
    }
    ls[tid] = s; ls2[tid] = s2;
    __syncthreads();
    if (tid < 32) {
        float S = 0.f, S2 = 0.f;
        #pragma unroll
        for (int r = 0; r < 8; ++r) { S += ls[r * 32 + tid]; S2 += ls2[r * 32 + tid]; }
        atomicAdd(&stats[tid], S);
        atomicAdd(&stats[32 + tid], S2);
    }
}

__global__ __launch_bounds__(256) void bn_relu_f32_kernel(
    float* __restrict__ out, const float* __restrict__ stats,
    const float* __restrict__ gamma, const float* __restrict__ beta)
{
    __shared__ float sc[32], sh[32];
    const int tid = threadIdx.x;
    if (tid < 32) {
        const float mean = stats[tid] * (1.0f / NN);
        const float var  = stats[32 + tid] * (1.0f / NN) - mean * mean;
        const float s = gamma[tid] * rsqrtf(var + EPSV);
        sc[tid] = s;
        sh[tid] = beta[tid] - mean * s;
    }
    __syncthreads();
    const int idx = blockIdx.x * 256 + tid;
    float4 v = ((float4*)out)[idx];
    const int cb = (idx & 7) << 2;
    v.x = fmaxf(v.x * sc[cb]     + sh[cb],     0.f);
    v.y = fmaxf(v.y * sc[cb + 1] + sh[cb + 1], 0.f);
    v.z = fmaxf(v.z * sc[cb + 2] + sh[cb + 2], 0.f);
    v.w = fmaxf(v.w * sc[cb + 3] + sh[cb + 3], 0.f);
    ((float4*)out)[idx] = v;
}

// ===========================================================================
extern "C" void kernel_launch(void* const* d_in, const int* in_sizes, int n_in,
                              void* d_out, int out_size, void* d_ws, size_t ws_size,
                              hipStream_t stream) {
    const float* data   = (const float*)d_in[0];
    const float* weight = (const float*)d_in[1];
    const float* gamma  = (const float*)d_in[2];
    const float* beta   = (const float*)d_in[3];
    const int*   neigh  = (const int*)d_in[4];
    float* out = (float*)d_out;
    char* ws = (char*)d_ws;
    float* stats = (float*)(ws + WS_STATS);

    if (ws_size >= WS_NEEDED) {
        unsigned short* wf = (unsigned short*)(ws + WS_WFRAG);
        unsigned long long* acc = (unsigned long long*)(ws + WS_ACC);
        const int n4 = (int)(WS_NEEDED / 16);
        zero_kernel<<<(n4 + 255) / 256, 256, 0, stream>>>((float4*)ws, n4);
        prep_wfrag<<<(KK * 3 * 512 + 255) / 256, 256, 0, stream>>>(weight, wf);
        scatter_kernel<<<NN / 128, 256, 0, stream>>>(data, wf, neigh, acc);
        stats_kernel<<<NN / 512, 256, 0, stream>>>(acc, stats);
        bn_relu_kernel<<<NN / 256, 256, 0, stream>>>(acc, out, stats, gamma, beta);
    } else {
        const int n4o = NN * CC / 4;
        zero_kernel<<<(n4o + 255) / 256, 256, 0, stream>>>((float4*)out, n4o);
        zero_kernel<<<1, 256, 0, stream>>>((float4*)stats, 16);
        scatter_f32_kernel<<<NN / 128, 256, 0, stream>>>(data, weight, neigh, out);
        stats_f32_kernel<<<NN / 512, 256, 0, stream>>>(out, stats);
        bn_relu_f32_kernel<<<(NN * CC / 4) / 256, 256, 0, stream>>>(out, stats, gamma, beta);
    }
}

// Round 8
// 272.260 us; speedup vs baseline: 6.4785x; 1.5651x over previous
//
#include <hip/hip_runtime.h>
#include <hip/hip_bf16.h>
#include <hip/hip_fp16.h>

#define NN 131072
#define KK 27
#define CC 32
#define EPSV 1e-5f

// workspace layout (bytes): [0,256) f32 stats, [256, 256+8.4MB) f16 accumulator
#define WS_STATS 0
#define WS_ACC   256
#define WS_NEEDED ((size_t)WS_ACC + (size_t)NN * CC * 2)

typedef __bf16 bf16x8 __attribute__((ext_vector_type(8)));
typedef short s16x8 __attribute__((ext_vector_type(8)));
typedef float f32x4 __attribute__((ext_vector_type(4)));

__device__ inline unsigned short f2bf(float f) {
    unsigned int u = __float_as_uint(f);
    u += 0x7FFF + ((u >> 16) & 1);   // round-to-nearest-even
    return (unsigned short)(u >> 16);
}

// ---------------------------------------------------------------------------
// Zero-fill via compute kernel (hipMemsetAsync == slow SDMA node in a graph).
__global__ __launch_bounds__(256) void zero_kernel(float4* __restrict__ p, int n4) {
    const int idx = blockIdx.x * 256 + threadIdx.x;
    const float4 z = {0.f, 0.f, 0.f, 0.f};
    if (idx < n4) p[idx] = z;
}

// ---------------------------------------------------------------------------
// Scatter with packed-f16 atomics — at the measured atomic sector-BW ceiling:
// 3.54M contributions x 64 B (2 sectors) = 226 MB at ~1.22 TB/s = ~185 us.
// (R1 f32 = 4 sectors, R7 u64-triple = 3 sectors, R6 uncoalesced = 32 B/op:
// all slower. Sector-write bandwidth at the coherence point is the invariant.)
//
// Channel permutation: logical out-channel c is computed by MFMA ch-half
// (c & 1) at physical column (c >> 1), so lane m holds the adjacent pair
// (2m, 2m+1) -> free __half2 pack, one global_atomic_pk_add_f16 per pair;
// a quad's 16 lanes cover one contiguous 64 B line of the destination row.
__global__ __launch_bounds__(256) void scatter_kernel(
    const float* __restrict__ data, const float* __restrict__ weight,
    const int* __restrict__ neigh, __half2* __restrict__ acc2)
{
    __shared__ __align__(16) unsigned short wfrag[KK * 2 * 64 * 8];   // 55296 B

    const int tid = threadIdx.x;
    const int lane = tid & 63;
    const int wv = tid >> 6;
    const int node_base = blockIdx.x * 128;

    // ---- Build permuted B-fragments from f32 weight [K][CIN][COUT] ----
    for (int p = tid; p < KK * 1024; p += 256) {
        const int k  = p >> 10;
        const int ci = (p >> 5) & 31;
        const int c  = p & 31;
        const unsigned short v = f2bf(weight[p]);
        const int chalf = c & 1;           // parity -> which MFMA
        const int col   = c >> 1;          // physical column 0..15
        const int fl = col | ((ci >> 3) << 4);
        const int j = ci & 7;
        wfrag[(((k << 1) | chalf) * 64 + fl) * 8 + j] = v;
    }

    // ---- A-fragments: A[m=lane&15][kel=quad*8+j], f32->bf16 inline ----
    const int quad = lane >> 4;
    const int m = lane & 15;
    s16x8 afr[2];
    #pragma unroll
    for (int g = 0; g < 2; ++g) {
        const int node = node_base + wv * 32 + g * 16 + m;
        const float* src = data + node * 32 + quad * 8;
        const float4 v0 = *(const float4*)(src);
        const float4 v1 = *(const float4*)(src + 4);
        s16x8 s;
        s[0] = (short)f2bf(v0.x); s[1] = (short)f2bf(v0.y);
        s[2] = (short)f2bf(v0.z); s[3] = (short)f2bf(v0.w);
        s[4] = (short)f2bf(v1.x); s[5] = (short)f2bf(v1.y);
        s[6] = (short)f2bf(v1.z); s[7] = (short)f2bf(v1.w);
        afr[g] = s;
    }

    __syncthreads();

    const int rq = quad << 2;              // C/D row base: row = rq + reg
    const f32x4 zero = {0.f, 0.f, 0.f, 0.f};

    for (int k = 0; k < KK; ++k) {
        int nj[2][4];
        #pragma unroll
        for (int g = 0; g < 2; ++g)
            #pragma unroll
            for (int r = 0; r < 4; ++r) {
                const int node = node_base + wv * 32 + g * 16 + rq + r;
                nj[g][r] = neigh[node * KK + k];
            }
        const s16x8 bs0 = *(const s16x8*)&wfrag[(((k << 1) | 0) * 64 + lane) * 8];
        const s16x8 bs1 = *(const s16x8*)&wfrag[(((k << 1) | 1) * 64 + lane) * 8];
        #pragma unroll
        for (int g = 0; g < 2; ++g) {
            const f32x4 d0 = __builtin_amdgcn_mfma_f32_16x16x32_bf16(
                __builtin_bit_cast(bf16x8, afr[g]), __builtin_bit_cast(bf16x8, bs0),
                zero, 0, 0, 0);
            const f32x4 d1 = __builtin_amdgcn_mfma_f32_16x16x32_bf16(
                __builtin_bit_cast(bf16x8, afr[g]), __builtin_bit_cast(bf16x8, bs1),
                zero, 0, 0, 0);
            #pragma unroll
            for (int r = 0; r < 4; ++r) {
                __half2 v;
                v.x = __float2half(d0[r]);   // logical channel 2m
                v.y = __float2half(d1[r]);   // logical channel 2m+1
                unsafeAtomicAdd(&acc2[nj[g][r] * 16 + m], v);
            }
        }
    }
}

// ---------------------------------------------------------------------------
// Per-channel sum/sumsq over the f16 accumulator. Block covers 512 rows.
__global__ __launch_bounds__(256) void stats_kernel(
    const __half2* __restrict__ acc2, float* __restrict__ stats)
{
    __shared__ float ls[16][33], ls2[16][33];   // [rowgroup][channel] (+pad)
    const int tid = threadIdx.x;
    const int c2 = tid & 15, rg = tid >> 4;     // 16 half2-cols x 16 rowgroups
    float sx = 0.f, sy = 0.f, s2x = 0.f, s2y = 0.f;
    const int row0 = blockIdx.x * 512;
    for (int it = 0; it < 32; ++it) {
        const __half2 h = acc2[(row0 + it * 16 + rg) * 16 + c2];
        const float vx = __half2float(h.x), vy = __half2float(h.y);
        sx += vx; sy += vy; s2x += vx * vx; s2y += vy * vy;
    }
    ls[rg][2 * c2] = sx;  ls[rg][2 * c2 + 1] = sy;
    ls2[rg][2 * c2] = s2x; ls2[rg][2 * c2 + 1] = s2y;
    __syncthreads();
    if (tid < 32) {
        float S = 0.f, S2 = 0.f;
        #pragma unroll
        for (int g = 0; g < 16; ++g) { S += ls[g][tid]; S2 += ls2[g][tid]; }
        atomicAdd(&stats[tid], S);
        atomicAdd(&stats[32 + tid], S2);
    }
}

// ---------------------------------------------------------------------------
// y = gamma*(x-mean)*rsqrt(var+eps)+beta, relu. Reads f16 accum, writes f32.
__global__ __launch_bounds__(256) void bn_relu_kernel(
    const __half2* __restrict__ acc2, float* __restrict__ out,
    const float* __restrict__ stats,
    const float* __restrict__ gamma, const float* __restrict__ beta)
{
    __shared__ float sc[32], sh[32];
    const int tid = threadIdx.x;
    if (tid < 32) {
        const float mean = stats[tid] * (1.0f / NN);
        const float var  = stats[32 + tid] * (1.0f / NN) - mean * mean;
        const float s = gamma[tid] * rsqrtf(var + EPSV);
        sc[tid] = s;
        sh[tid] = beta[tid] - mean * s;
    }
    __syncthreads();
    const int idx = blockIdx.x * 256 + tid;      // idx over groups of 4 half2
    const int c0 = (idx & 3) << 3;               // channel base within row
    const __half2 h4[4] = { acc2[idx * 4], acc2[idx * 4 + 1],
                            acc2[idx * 4 + 2], acc2[idx * 4 + 3] };
    float4 o0, o1;
    o0.x = fmaxf(__half2float(h4[0].x) * sc[c0]     + sh[c0],     0.f);
    o0.y = fmaxf(__half2float(h4[0].y) * sc[c0 + 1] + sh[c0 + 1], 0.f);
    o0.z = fmaxf(__half2float(h4[1].x) * sc[c0 + 2] + sh[c0 + 2], 0.f);
    o0.w = fmaxf(__half2float(h4[1].y) * sc[c0 + 3] + sh[c0 + 3], 0.f);
    o1.x = fmaxf(__half2float(h4[2].x) * sc[c0 + 4] + sh[c0 + 4], 0.f);
    o1.y = fmaxf(__half2float(h4[2].y) * sc[c0 + 5] + sh[c0 + 5], 0.f);
    o1.z = fmaxf(__half2float(h4[3].x) * sc[c0 + 6] + sh[c0 + 6], 0.f);
    o1.w = fmaxf(__half2float(h4[3].y) * sc[c0 + 7] + sh[c0 + 7], 0.f);
    ((float4*)out)[idx * 2]     = o0;
    ((float4*)out)[idx * 2 + 1] = o1;
}

// ===========================================================================
// Fallback (f32 atomics into d_out) — only if ws is too small.
__global__ __launch_bounds__(256) void scatter_f32_kernel(
    const float* __restrict__ data, const float* __restrict__ weight,
    const int* __restrict__ neigh, float* __restrict__ out)
{
    __shared__ unsigned short wfrag[KK * 2 * 64 * 8];
    const int tid = threadIdx.x;
    const int lane = tid & 63;
    const int wv = tid >> 6;
    const int node_base = blockIdx.x * 128;
    for (int p = tid; p < KK * 1024; p += 256) {
        const int k  = p >> 10;
        const int ci = (p >> 5) & 31;
        const int c  = p & 31;
        const unsigned short v = f2bf(weight[p]);
        const int chalf = c >> 4;
        const int fl = (c & 15) | ((ci >> 3) << 4);
        const int j = ci & 7;
        wfrag[(((k << 1) | chalf) * 64 + fl) * 8 + j] = v;
    }
    const int quad = lane >> 4;
    const int m = lane & 15;
    s16x8 afr[2];
    #pragma unroll
    for (int g = 0; g < 2; ++g) {
        const int node = node_base + wv * 32 + g * 16 + m;
        const float* src = data + node * 32 + quad * 8;
        const float4 v0 = *(const float4*)(src);
        const float4 v1 = *(const float4*)(src + 4);
        s16x8 s;
        s[0] = (short)f2bf(v0.x); s[1] = (short)f2bf(v0.y);
        s[2] = (short)f2bf(v0.z); s[3] = (short)f2bf(v0.w);
        s[4] = (short)f2bf(v1.x); s[5] = (short)f2bf(v1.y);
        s[6] = (short)f2bf(v1.z); s[7] = (short)f2bf(v1.w);
        afr[g] = s;
    }
    __syncthreads();
    const int rq = quad << 2;
    const f32x4 zero = {0.f, 0.f, 0.f, 0.f};
    for (int k = 0; k < KK; ++k) {
        int nj[2][4];
        #pragma unroll
        for (int g = 0; g < 2; ++g)
            #pragma unroll
            for (int r = 0; r < 4; ++r) {
                const int node = node_base + wv * 32 + g * 16 + rq + r;
                nj[g][r] = neigh[node * KK + k];
            }
        #pragma unroll
        for (int ch = 0; ch < 2; ++ch) {
            const s16x8 bs = *(const s16x8*)&wfrag[((((k << 1) | ch)) * 64 + lane) * 8];
            const bf16x8 bfr = __builtin_bit_cast(bf16x8, bs);
            const int c = (ch << 4) | m;
            #pragma unroll
            for (int g = 0; g < 2; ++g) {
                f32x4 a2 = __builtin_amdgcn_mfma_f32_16x16x32_bf16(
                    __builtin_bit_cast(bf16x8, afr[g]), bfr, zero, 0, 0, 0);
                #pragma unroll
                for (int r = 0; r < 4; ++r)
                    __hip_atomic_fetch_add(&out[nj[g][r] * 32 + c], a2[r],
                                           __ATOMIC_RELAXED, __HIP_MEMORY_SCOPE_AGENT);
            }
        }
    }
}

__global__ __launch_bounds__(256) void stats_f32_kernel(
    const float* __restrict__ out, float* __restrict__ stats)
{
    __shared__ float ls[256], ls2[256];
    const int tid = threadIdx.x;
    const int c = tid & 31, rg = tid >> 5;
    float s = 0.f, s2 = 0.f;
    const int row0 = blockIdx.x * 512;
    for (int it = 0; it < 64; ++it) {
        const float v = out[(row0 + it * 8 + rg) * 32 + c];
        s += v; s2 += v * v;
    }
    ls[tid] = s; ls2[tid] = s2;
    __syncthreads();
    if (tid < 32) {
        float S = 0.f, S2 = 0.f;
        #pragma unroll
        for (int r = 0; r < 8; ++r) { S += ls[r * 32 + tid]; S2 += ls2[r * 32 + tid]; }
        atomicAdd(&stats[tid], S);
        atomicAdd(&stats[32 + tid], S2);
    }
}

__global__ __launch_bounds__(256) void bn_relu_f32_kernel(
    float* __restrict__ out, const float* __restrict__ stats,
    const float* __restrict__ gamma, const float* __restrict__ beta)
{
    __shared__ float sc[32], sh[32];
    const int tid = threadIdx.x;
    if (tid < 32) {
        const float mean = stats[tid] * (1.0f / NN);
        const float var  = stats[32 + tid] * (1.0f / NN) - mean * mean;
        const float s = gamma[tid] * rsqrtf(var + EPSV);
        sc[tid] = s;
        sh[tid] = beta[tid] - mean * s;
    }
    __syncthreads();
    const int idx = blockIdx.x * 256 + tid;
    float4 v = ((float4*)out)[idx];
    const int cb = (idx & 7) << 2;
    v.x = fmaxf(v.x * sc[cb]     + sh[cb],     0.f);
    v.y = fmaxf(v.y * sc[cb + 1] + sh[cb + 1], 0.f);
    v.z = fmaxf(v.z * sc[cb + 2] + sh[cb + 2], 0.f);
    v.w = fmaxf(v.w * sc[cb + 3] + sh[cb + 3], 0.f);
    ((float4*)out)[idx] = v;
}

// ===========================================================================
extern "C" void kernel_launch(void* const* d_in, const int* in_sizes, int n_in,
                              void* d_out, int out_size, void* d_ws, size_t ws_size,
                              hipStream_t stream) {
    const float* data   = (const float*)d_in[0];
    const float* weight = (const float*)d_in[1];
    const float* gamma  = (const float*)d_in[2];
    const float* beta   = (const float*)d_in[3];
    const int*   neigh  = (const int*)d_in[4];
    float* out = (float*)d_out;
    char* ws = (char*)d_ws;
    float* stats = (float*)(ws + WS_STATS);

    if (ws_size >= WS_NEEDED) {
        __half2* acc2 = (__half2*)(ws + WS_ACC);
        // zero stats (256 B) + f16 accumulator (8.4 MB) with a store kernel
        const int n4 = (int)(WS_NEEDED / 16);            // WS_NEEDED is 16B-aligned
        zero_kernel<<<(n4 + 255) / 256, 256, 0, stream>>>((float4*)ws, n4);
        scatter_kernel<<<NN / 128, 256, 0, stream>>>(data, weight, neigh, acc2);
        stats_kernel<<<NN / 512, 256, 0, stream>>>(acc2, stats);
        bn_relu_kernel<<<(NN * CC / 8) / 256, 256, 0, stream>>>(acc2, out, stats, gamma, beta);
    } else {
        const int n4o = NN * CC / 4;                     // zero d_out (16.8 MB)
        zero_kernel<<<(n4o + 255) / 256, 256, 0, stream>>>((float4*)out, n4o);
        zero_kernel<<<1, 256, 0, stream>>>((float4*)stats, 16);
        scatter_f32_kernel<<<NN / 128, 256, 0, stream>>>(data, weight, neigh, out);
        stats_f32_kernel<<<NN / 512, 256, 0, stream>>>(out, stats);
        bn_relu_f32_kernel<<<(NN * CC / 4) / 256, 256, 0, stream>>>(out, stats, gamma, beta);
    }
}